// Round 4
// baseline (30110.757 us; speedup 1.0000x reference)
//
#include <hip/hip_runtime.h>
#include <stdint.h>

// ---------------------------------------------------------------------------
// TopDownLSTM: T=256, B=64, I=512, H=1024, L=3.
// Persistent kernel: 256 blocks x 512 threads (8 waves). Block pb owns h-cols
// [4pb, 4pb+4) => z-cols {g*1024 + 4pb + j}. ALL WEIGHTS LIVE IN VGPRs:
// 30 bf16x8 fragments/thread (120 VGPRs), loaded once from fp32 at start.
// Two grid-barrier phases per timestep (skewed):
//   phase A(t): cell0(t) and cell2(t-1)     [share h1(t-1) A-read]
//   phase B(t): cell1(t)
// h mirrors: 3-slot bf16 ring, slot(t) = t % 3.
// ---------------------------------------------------------------------------

using bf16x8 = __attribute__((ext_vector_type(8))) short;   // 8 bf16 (4 VGPRs)
using f32x4  = __attribute__((ext_vector_type(4))) float;   // MFMA acc

#define DEVINL __device__ __forceinline__

constexpr int T_ = 256;
constexpr int NBLK = 256;

// Workspace layout (bytes). Total ~18.5 MB.
constexpr size_t XB_ELEMS   = 256ull * 64 * 512;            // x bf16 mirror
constexpr size_t HB_OFF_B   = XB_ELEMS * 2;                 // 16,777,216
constexpr size_t HSLOT      = 3ull * 64 * 1024;             // elems per ring slot
constexpr size_t SYNC_OFF_B = HB_OFF_B + 3ull * HSLOT * 2;  // 17,956,864
constexpr size_t SYNC_BYTES = 520ull * 128 * 4;             // 520 barriers x 8 grp x 64B

DEVINL ushort f2bf(float f) {                     // fp32 -> bf16 RNE
  uint32_t x = __float_as_uint(f);
  uint32_t r = (x + 0x7fffu + ((x >> 16) & 1u)) >> 16;
  return (ushort)r;
}
DEVINL float sigf(float x) { return 1.0f / (1.0f + __expf(-x)); }
DEVINL float tanhf_(float x) {                    // overflow-safe tanh
  float ax = fabsf(x);
  float e  = __expf(-2.0f * ax);
  float t  = (1.0f - e) / (1.0f + e);
  return copysignf(t, x);
}

// x fp32 -> bf16 (whole [T][64][512] tensor). grid 8192 x 256, exact.
__global__ void cvt_x(const float* __restrict__ x, ushort* __restrict__ xb) {
  int i = blockIdx.x * blockDim.x + threadIdx.x;
  float4 v = reinterpret_cast<const float4*>(x)[i];
  ushort4 u;
  u.x = f2bf(v.x); u.y = f2bf(v.y); u.z = f2bf(v.z); u.w = f2bf(v.w);
  reinterpret_cast<ushort4*>(xb)[i] = u;
}

// ---------------------------------------------------------------------------
// GEMM piece with REGISTER-RESIDENT B: acc[64x16] += A[64xK] * W[Kx16].
// Wave w handles k-slice [K/8*w, K/8*(w+1)); B-frags wf[BASE..BASE+NKS).
// A row-major bf16. A-frag: row = r16+16m, k = k0 + 8q + i.
// ---------------------------------------------------------------------------
template <int NKS, int BASE>
DEVINL void gemm_r(f32x4 (&acc)[4], const bf16x8 (&wf)[30],
                   const ushort* __restrict__ A, int lda, int w, int r16, int q) {
#pragma unroll
  for (int ks = 0; ks < NKS; ++ks) {
    const int k0 = NKS * 32 * w + 32 * ks;
    const ushort* ap = A + r16 * lda + k0 + q * 8;
    bf16x8 a0 = *reinterpret_cast<const bf16x8*>(ap);
    bf16x8 a1 = *reinterpret_cast<const bf16x8*>(ap + 16 * lda);
    bf16x8 a2 = *reinterpret_cast<const bf16x8*>(ap + 32 * lda);
    bf16x8 a3 = *reinterpret_cast<const bf16x8*>(ap + 48 * lda);
    acc[0] = __builtin_amdgcn_mfma_f32_16x16x32_bf16(a0, wf[BASE + ks], acc[0], 0, 0, 0);
    acc[1] = __builtin_amdgcn_mfma_f32_16x16x32_bf16(a1, wf[BASE + ks], acc[1], 0, 0, 0);
    acc[2] = __builtin_amdgcn_mfma_f32_16x16x32_bf16(a2, wf[BASE + ks], acc[2], 0, 0, 0);
    acc[3] = __builtin_amdgcn_mfma_f32_16x16x32_bf16(a3, wf[BASE + ks], acc[3], 0, 0, 0);
  }
}

// Grid barrier: 8 groups x 32 blocks, fresh counter per instance. Release
// fence drains producer stores; acquire fence invalidates L1/L2 for consumers.
DEVINL void grid_barrier(int* __restrict__ syncp, int bar) {
  __builtin_amdgcn_fence(__ATOMIC_RELEASE, "agent");
  __syncthreads();
  int* base = syncp + (size_t)bar * 128;          // 8 groups x 16 ints (64B apart)
  if (threadIdx.x == 0)
    __hip_atomic_fetch_add(base + (blockIdx.x & 7) * 16, 1,
                           __ATOMIC_RELAXED, __HIP_MEMORY_SCOPE_AGENT);
  if (threadIdx.x < 8) {
    while (__hip_atomic_load(base + threadIdx.x * 16,
                             __ATOMIC_RELAXED, __HIP_MEMORY_SCOPE_AGENT) < (NBLK / 8))
      __builtin_amdgcn_s_sleep(1);
  }
  __syncthreads();
  __builtin_amdgcn_fence(__ATOMIC_ACQUIRE, "agent");
}

// ---------------------------------------------------------------------------
// Persistent kernel. Weights arrive as raw fp32 [K][4096] matrices.
// ---------------------------------------------------------------------------
__global__ void __launch_bounds__(512, 2)
lstm_persist(const ushort* __restrict__ xb, ushort* __restrict__ Hb,
             int* __restrict__ syncp, float* __restrict__ outp,
             const float* __restrict__ h0, const float* __restrict__ c0,
             const int* __restrict__ len,
             const float* __restrict__ Whh0, const float* __restrict__ Wth0,
             const float* __restrict__ Whh1, const float* __restrict__ Wbh1,
             const float* __restrict__ Wth1, const float* __restrict__ Whh2,
             const float* __restrict__ Wih2, const float* __restrict__ Wbh0,
             const float* __restrict__ b0v, const float* __restrict__ b1v,
             const float* __restrict__ b2v) {
  const int pb = blockIdx.x, tid = threadIdx.x;
  const int w = tid >> 6, lane = tid & 63, r16 = lane & 15, q = lane >> 4;
  __shared__ float zp[8][64][17];                 // split-K partials, 34.8 KB

  // ---- load this thread's 30 persistent B-fragments (120 VGPRs) ----------
  // Fragment (piece p, ks): elem i = W[k][colW], k = K/8*w + 32ks + 8q + i,
  // colW = (r16>>2)*1024 + 4*pb + (r16&3).  Pieces: 0 Whh0, 1 Wth0, 2 Whh1,
  // 3 Wbh1, 4 Wth1, 5 Whh2, 6 Wih2 (K=1024, 4 frags) ; 7 Wbh0 (K=512, 2).
  const float* wsrc[8] = {Whh0, Wth0, Whh1, Wbh1, Wth1, Whh2, Wih2, Wbh0};
  const int colW = (r16 >> 2) * 1024 + 4 * pb + (r16 & 3);
  bf16x8 wf[30];
#pragma unroll
  for (int p = 0; p < 7; ++p)
#pragma unroll
    for (int ks = 0; ks < 4; ++ks) {
      bf16x8 v;
#pragma unroll
      for (int i = 0; i < 8; ++i)
        v[i] = (short)f2bf(wsrc[p][(size_t)(128 * w + 32 * ks + 8 * q + i) * 4096 + colW]);
      wf[p * 4 + ks] = v;
    }
#pragma unroll
  for (int ks = 0; ks < 2; ++ks) {
    bf16x8 v;
#pragma unroll
    for (int i = 0; i < 8; ++i)
      v[i] = (short)f2bf(wsrc[7][(size_t)(64 * w + 32 * ks + 8 * q + i) * 4096 + colW]);
    wf[28 + ks] = v;
  }

  // ---- per-thread gate state (tid < 256): one (row,col) for all 3 layers --
  const int gr = tid >> 2, gj = tid & 3;
  const int gcol = 4 * pb + gj;
  int   mylen = 0;
  float h0r = 0, h1r = 0, h2r = 0, c0r = 0, c1r = 0, c2r = 0;
  float bb0[4] = {0,0,0,0}, bb1[4] = {0,0,0,0}, bb2[4] = {0,0,0,0};
  if (tid < 256) {
    mylen = len[gr];
    h0r = h0[(0 * 64 + gr) * 1024 + gcol]; c0r = c0[(0 * 64 + gr) * 1024 + gcol];
    h1r = h0[(1 * 64 + gr) * 1024 + gcol]; c1r = c0[(1 * 64 + gr) * 1024 + gcol];
    h2r = h0[(2 * 64 + gr) * 1024 + gcol]; c2r = c0[(2 * 64 + gr) * 1024 + gcol];
#pragma unroll
    for (int g = 0; g < 4; ++g) {
      bb0[g] = b0v[g * 1024 + gcol];
      bb1[g] = b1v[g * 1024 + gcol];
      bb2[g] = b2v[g * 1024 + gcol];
    }
    ushort* hs = Hb + 2 * HSLOT;                  // slot 2 = state at t=-1
    hs[(0 * 64 + gr) * 1024 + gcol] = f2bf(h0r);
    hs[(1 * 64 + gr) * 1024 + gcol] = f2bf(h1r);
    hs[(2 * 64 + gr) * 1024 + gcol] = f2bf(h2r);
  }
  grid_barrier(syncp, 0);

  // Split-K reduce + gates + masked update + bf16 mirror (+ optional fp32 out).
  auto do_cell = [&](f32x4 (&acc)[4], const float* bb, float& hr, float& cr,
                     ushort* hbw, bool upd, float* ow) {
#pragma unroll
    for (int mf = 0; mf < 4; ++mf)
#pragma unroll
      for (int rg = 0; rg < 4; ++rg)
        zp[w][mf * 16 + q * 4 + rg][r16] = acc[mf][rg];
    __syncthreads();
    if (tid < 256) {
      float z0 = bb[0], z1 = bb[1], z2 = bb[2], z3 = bb[3];
#pragma unroll
      for (int ww = 0; ww < 8; ++ww) {
        const float* zr = &zp[ww][gr][0];
        z0 += zr[gj]; z1 += zr[4 + gj]; z2 += zr[8 + gj]; z3 += zr[12 + gj];
      }
      float fg = sigf(z0), ig = sigf(z1), og = sigf(z2), gg = tanhf_(z3);
      float cn = fg * cr + ig * gg;
      float hn = og * tanhf_(cn);
      if (upd) { cr = cn; hr = hn; }              // freeze when t >= length
      hbw[gr * 1024 + gcol] = f2bf(hr);
      if (ow) ow[gr * 1024 + gcol] = hr;
    }
    __syncthreads();                              // zp reused by next cell
  };

  for (int t = 0; t < T_; ++t) {
    const int sC  = t % 3;                        // slot(t)
    const int sP  = (t + 2) % 3;                  // slot(t-1)
    const int sPP = (t + 1) % 3;                  // slot(t-2)
    ushort* HS_C        = Hb + (size_t)sC * HSLOT;
    const ushort* HS_P  = Hb + (size_t)sP * HSLOT;
    const ushort* HS_PP = Hb + (size_t)sPP * HSLOT;

    { // ---- phase A: cell0(t) + cell2(t-1) ---------------------------------
      f32x4 aA[4] = {{0,0,0,0},{0,0,0,0},{0,0,0,0},{0,0,0,0}};
      f32x4 aC[4] = {{0,0,0,0},{0,0,0,0},{0,0,0,0},{0,0,0,0}};
      gemm_r<4, 0 >(aA, wf, HS_P + 0 * 65536, 1024, w, r16, q);   // Whh0 x h0(t-1)
      gemm_r<4, 4 >(aA, wf, HS_P + 1 * 65536, 1024, w, r16, q);   // Wth0 x h1(t-1)
      gemm_r<2, 28>(aA, wf, xb + (size_t)t * 32768, 512, w, r16, q); // Wbh0 x x_t
      if (t > 0) {
        gemm_r<4, 20>(aC, wf, HS_PP + 2 * 65536, 1024, w, r16, q); // Whh2 x h2(t-2)
        gemm_r<4, 24>(aC, wf, HS_P  + 1 * 65536, 1024, w, r16, q); // Wih2 x h1(t-1)
      }
      do_cell(aA, bb0, h0r, c0r, HS_C + 0 * 65536, t < mylen, nullptr);
      if (t > 0)
        do_cell(aC, bb2, h2r, c2r, Hb + (size_t)sP * HSLOT + 2 * 65536,
                (t - 1) < mylen, outp + (size_t)(t - 1) * 65536);
      grid_barrier(syncp, 1 + 2 * t);
    }
    { // ---- phase B: cell1(t) ----------------------------------------------
      f32x4 aB[4] = {{0,0,0,0},{0,0,0,0},{0,0,0,0},{0,0,0,0}};
      gemm_r<4, 8 >(aB, wf, HS_P + 1 * 65536, 1024, w, r16, q);   // Whh1 x h1(t-1)
      gemm_r<4, 12>(aB, wf, HS_C + 0 * 65536, 1024, w, r16, q);   // Wbh1 x h0(t)
      gemm_r<4, 16>(aB, wf, HS_P + 2 * 65536, 1024, w, r16, q);   // Wth1 x h2(t-1)
      do_cell(aB, bb1, h1r, c1r, HS_C + 1 * 65536, t < mylen, nullptr);
      grid_barrier(syncp, 2 + 2 * t);
    }
  }

  { // ---- epilogue: cell2(T-1) ---------------------------------------------
    const int sP = (T_ + 2) % 3, sPP = (T_ + 1) % 3;
    f32x4 aC[4] = {{0,0,0,0},{0,0,0,0},{0,0,0,0},{0,0,0,0}};
    gemm_r<4, 20>(aC, wf, Hb + (size_t)sPP * HSLOT + 2 * 65536, 1024, w, r16, q);
    gemm_r<4, 24>(aC, wf, Hb + (size_t)sP  * HSLOT + 1 * 65536, 1024, w, r16, q);
    do_cell(aC, bb2, h2r, c2r, Hb + (size_t)sP * HSLOT + 2 * 65536,
            (T_ - 1) < mylen, outp + (size_t)(T_ - 1) * 65536);
  }

  if (tid < 256) {                                // final Ht, C (fp32 from regs)
    float* HtO = outp + (size_t)T_ * 65536;
    float* CO  = HtO + 3 * 65536;
    HtO[(0 * 64 + gr) * 1024 + gcol] = h0r;
    HtO[(1 * 64 + gr) * 1024 + gcol] = h1r;
    HtO[(2 * 64 + gr) * 1024 + gcol] = h2r;
    CO[(0 * 64 + gr) * 1024 + gcol] = c0r;
    CO[(1 * 64 + gr) * 1024 + gcol] = c1r;
    CO[(2 * 64 + gr) * 1024 + gcol] = c2r;
  }
}

// ---------------------------------------------------------------------------
extern "C" void kernel_launch(void* const* d_in, const int* in_sizes, int n_in,
                              void* d_out, int out_size, void* d_ws, size_t ws_size,
                              hipStream_t stream) {
  (void)in_sizes; (void)n_in; (void)out_size; (void)ws_size;
  const float* x    = (const float*)d_in[0];
  const int*   len  = (const int*)d_in[1];
  const float* h0   = (const float*)d_in[2];
  const float* c0   = (const float*)d_in[3];
  const float* Wbh0 = (const float*)d_in[4];
  const float* Whh0 = (const float*)d_in[5];
  const float* Wth0 = (const float*)d_in[6];
  const float* b0   = (const float*)d_in[7];
  const float* Wbh1 = (const float*)d_in[8];
  const float* Whh1 = (const float*)d_in[9];
  const float* Wth1 = (const float*)d_in[10];
  const float* b1   = (const float*)d_in[11];
  const float* Wih2 = (const float*)d_in[12];
  const float* Whh2 = (const float*)d_in[13];
  const float* b2   = (const float*)d_in[14];

  ushort* xb    = (ushort*)d_ws;
  ushort* Hb    = (ushort*)((char*)d_ws + HB_OFF_B);
  int*    syncp = (int*)((char*)d_ws + SYNC_OFF_B);

  cvt_x<<<8192, 256, 0, stream>>>(x, xb);
  (void)hipMemsetAsync(syncp, 0, SYNC_BYTES, stream);

  lstm_persist<<<NBLK, 512, 0, stream>>>(xb, Hb, syncp, (float*)d_out,
                                         h0, c0, len,
                                         Whh0, Wth0, Whh1, Wbh1, Wth1, Whh2,
                                         Wih2, Wbh0, b0, b1, b2);
}